// Round 5
// baseline (869.539 us; speedup 1.0000x reference)
//
#include <hip/hip_runtime.h>
#include <cmath>

// Problem constants: V=50000, E=300, H=512, L=6, N=8192, K=4
#define VSZ  50000
#define EDIM 300
#define EPAD 320      // E padded to multiple of 64
#define HDIM 512
#define LVLS 6
#define NN   8192
#define KCH  4

// MFMA GEMM tile: 128x128 block, BK=64, 4 waves of 64x64 (4x4 grid of 16x16x32 MFMA)
#define BM 128
#define BN 128
#define BKE 64

typedef __attribute__((ext_vector_type(8))) short bf16x8;
typedef __attribute__((ext_vector_type(8))) unsigned short us8;
typedef __attribute__((ext_vector_type(4))) float f32x4;

__device__ __forceinline__ float sigf(float x) { return 1.0f / (1.0f + expf(-x)); }

__device__ __forceinline__ unsigned short f2bf(float f) {
    unsigned u = __float_as_uint(f);
    u += 0x7FFF + ((u >> 16) & 1);           // RNE
    return (unsigned short)(u >> 16);
}
__device__ __forceinline__ float bf2f(unsigned short h) {
    return __uint_as_float(((unsigned)h) << 16);
}

// ---- convert embed [V][E] f32 -> [V][EPAD] bf16 (zero-padded) ----
__global__ __launch_bounds__(256) void econv_k(
    const float* __restrict__ in, unsigned short* __restrict__ out)
{
    int t = blockIdx.x * 256 + threadIdx.x;   // V*EPAD total
    int e = t % EPAD;
    int v = t / EPAD;
    out[t] = (e < EDIM) ? f2bf(in[(size_t)v * EDIM + e]) : (unsigned short)0;
}

// ---- transpose+convert weights: out[n][k] = bf16(in[k][n]), zero for k>=Kreal ----
__global__ __launch_bounds__(256) void wconv_k(
    const float* __restrict__ in, unsigned short* __restrict__ out,
    int Kreal, int Ksp, int Nd)
{
    int t = blockIdx.x * 256 + threadIdx.x;   // Nd*Ksp total, k fast
    int k = t % Ksp;
    int n = t / Ksp;
    out[t] = (k < Kreal) ? f2bf(in[(size_t)k * Nd + n]) : (unsigned short)0;
}

// MODEA: 0 = dense A rows, 1 = gathered rows via aidx
// EPI  : 0 = C = bf16(acc)
//        1 = C = bf16(acc*rowscale[row] + (col<1536 ? b_iou[col] : b_f[col-1536]))
// BK=64: LDS granule = 16 B (8 ushort). Chunk c of a tile (row=c>>3, slot=c&7)
// holds global K-granule kg = slot ^ (row&7); staged via global_load_lds
// (identity LDS placement -> wave-uniform dest + lane*16). Epilogue: acc -> bf16
// into the same 32 KB LDS (XOR-granule swizzle on row&7), then 128 B/thread
// contiguous readback and dwordx4 global stores.
template <int MODEA, int EPI, int NCHUNK>
__global__ __launch_bounds__(256, 4) void mgemm_k(
    const unsigned short* __restrict__ Ab,
    const int* __restrict__ aidx, const float* __restrict__ rowscale,
    const unsigned short* __restrict__ Bt,
    const float* __restrict__ b_iou, const float* __restrict__ b_f,
    unsigned short* __restrict__ C, int ldc, int Ks)
{
    __shared__ __align__(16) unsigned short smem[2 * BM * BKE];  // 32 KB
    unsigned short* As = smem;               // [BM*BKE]
    unsigned short* Bs = smem + BM * BKE;    // [BN*BKE]

    const int tid  = threadIdx.x;
    const int wave = tid >> 6;
    const int lane = tid & 63;
    const int quad = lane >> 4;
    const int mcol = lane & 15;
    const int wm   = (wave >> 1) * 64;
    const int wn   = (wave & 1) * 64;
    const int tile_m = blockIdx.y * BM;

    // staging: 4 chunks per thread per matrix; chunk c_j = tid + 256*j
    int arow[4]; int kgo[4];
#pragma unroll
    for (int j = 0; j < 4; ++j) {
        int c   = tid + 256 * j;
        int row = c >> 3;
        kgo[j]  = ((c & 7) ^ (row & 7)) * 8;
        arow[j] = row;
    }
    const unsigned short* asrc[4];
#pragma unroll
    for (int j = 0; j < 4; ++j) {
        int gr = MODEA ? aidx[tile_m + arow[j]] : (tile_m + arow[j]);
        asrc[j] = Ab + (size_t)gr * Ks + kgo[j];
    }

    for (int nc = 0; nc < NCHUNK; ++nc) {
        const int tile_n = (blockIdx.x * NCHUNK + nc) * BN;
        const unsigned short* bsrc[4];
#pragma unroll
        for (int j = 0; j < 4; ++j)
            bsrc[j] = Bt + (size_t)(tile_n + arow[j]) * Ks + kgo[j];

        f32x4 acc[4][4] = {};

        for (int k0 = 0; k0 < Ks; k0 += BKE) {
#pragma unroll
            for (int j = 0; j < 4; ++j) {
                __attribute__((address_space(3))) unsigned int* dA =
                    (__attribute__((address_space(3))) unsigned int*)(As + (wave * 64 + 256 * j) * 8);
                __attribute__((address_space(3))) unsigned int* dB =
                    (__attribute__((address_space(3))) unsigned int*)(Bs + (wave * 64 + 256 * j) * 8);
                __builtin_amdgcn_global_load_lds(
                    (const __attribute__((address_space(1))) unsigned int*)(asrc[j] + k0), dA, 16, 0, 0);
                __builtin_amdgcn_global_load_lds(
                    (const __attribute__((address_space(1))) unsigned int*)(bsrc[j] + k0), dB, 16, 0, 0);
            }
            __syncthreads();

#pragma unroll
            for (int kh = 0; kh < 2; ++kh) {
                bf16x8 afr[4], bfr[4];
#pragma unroll
                for (int mt = 0; mt < 4; ++mt) {
                    int rw = wm + mt * 16 + mcol;
                    int p  = (kh * 4 + quad) ^ (rw & 7);
                    afr[mt] = *(const bf16x8*)(As + (rw * 8 + p) * 8);
                }
#pragma unroll
                for (int nt = 0; nt < 4; ++nt) {
                    int rw = wn + nt * 16 + mcol;
                    int p  = (kh * 4 + quad) ^ (rw & 7);
                    bfr[nt] = *(const bf16x8*)(Bs + (rw * 8 + p) * 8);
                }
#pragma unroll
                for (int mt = 0; mt < 4; ++mt)
#pragma unroll
                    for (int nt = 0; nt < 4; ++nt)
                        acc[mt][nt] = __builtin_amdgcn_mfma_f32_16x16x32_bf16(
                            afr[mt], bfr[nt], acc[mt][nt], 0, 0, 0);
            }
            __syncthreads();
        }

        // ---- epilogue: stage bf16 C-tile in LDS (row-major 128x128, 16B-granule
        // XOR swizzle on row&7), then contiguous readback + dwordx4 stores ----
        unsigned short* Ct = smem;   // 32 KB = 128*128 ushort
#pragma unroll
        for (int mt = 0; mt < 4; ++mt) {
            const int rl = wm + mt * 16 + quad * 4;     // local row base
            float4 ts = make_float4(1.f, 1.f, 1.f, 1.f);
            if (EPI == 1) ts = *(const float4*)&rowscale[tile_m + rl];
            const float tsv[4] = {ts.x, ts.y, ts.z, ts.w};
#pragma unroll
            for (int nt = 0; nt < 4; ++nt) {
                const int cl = wn + nt * 16 + mcol;     // local col
                float bv = 0.0f;
                if (EPI == 1) {
                    int col = tile_n + cl;
                    bv = (col < 3 * HDIM) ? b_iou[col] : b_f[col - 3 * HDIM];
                }
#pragma unroll
                for (int r = 0; r < 4; ++r) {
                    int row = rl + r;
                    int g   = (cl >> 3) ^ (row & 7);    // swizzled 16B granule
                    float v = acc[mt][nt][r];
                    if (EPI == 1) v = v * tsv[r] + bv;
                    Ct[row * BN + g * 8 + (cl & 7)] = f2bf(v);
                }
            }
        }
        __syncthreads();
        {
            const int row  = tid >> 1;
            const int half = tid & 1;
            unsigned short* gp = C + (size_t)(tile_m + row) * ldc + tile_n + half * 64;
#pragma unroll
            for (int v = 0; v < 8; ++v) {
                int g  = half * 8 + v;
                int gs = g ^ (row & 7);
                *(us8*)(gp + v * 8) = *(const us8*)(Ct + row * BN + gs * 8);
            }
        }
        __syncthreads();   // LDS reused for staging next nc chunk
    }
}

// fused child-sum + fc + gates (non-leaf).
// iouxW row: bf16 [i|o|u|xwf+bf] (2048). Z row: bf16 [h@U_iou (1536) | h@U_f (512)].
//   ia = i + sum_k m_k * Zi[c_k] ; fc = sum_k sigf(xw + m_k*Zf[c_k]) * m_k * c_prev[c_k]
//   c = sigf(ia)*tanh(ua) + fc ; h = sigf(oa)*tanh(c)
template <bool LAST>
__global__ __launch_bounds__(256) void gatefc_k(
    const unsigned short* __restrict__ iouxW, const unsigned short* __restrict__ Z,
    const int* __restrict__ cidx, const float* __restrict__ cmask,
    const float* __restrict__ c_prev,
    float* __restrict__ c_new, unsigned short* __restrict__ hb_new,
    float* __restrict__ h_out)
{
    int t  = blockIdx.x * 256 + threadIdx.x;   // NN*HDIM/8 threads
    int n  = t >> 6;
    int j8 = (t & 63) << 3;
    const unsigned short* xr = iouxW + (size_t)n * 4 * HDIM + j8;
    us8 xi = *(const us8*)xr;
    us8 xo = *(const us8*)(xr + HDIM);
    us8 xu = *(const us8*)(xr + 2 * HDIM);
    us8 xf = *(const us8*)(xr + 3 * HDIM);
    float ia[8], oa[8], ua[8], xw[8], fc[8];
#pragma unroll
    for (int j = 0; j < 8; ++j) {
        ia[j] = bf2f(xi[j]); oa[j] = bf2f(xo[j]);
        ua[j] = bf2f(xu[j]); xw[j] = bf2f(xf[j]);
        fc[j] = 0.0f;
    }
    int4   ci = *(const int4*)&cidx[n * KCH];
    float4 cm = *(const float4*)&cmask[n * KCH];
    const int   cia[4] = {ci.x, ci.y, ci.z, ci.w};
    const float cma[4] = {cm.x, cm.y, cm.z, cm.w};
#pragma unroll
    for (int k = 0; k < KCH; ++k) {
        const float m = cma[k];
        const unsigned short* zr = Z + (size_t)cia[k] * 4 * HDIM + j8;
        us8 zi = *(const us8*)zr;
        us8 zo = *(const us8*)(zr + HDIM);
        us8 zu = *(const us8*)(zr + 2 * HDIM);
        us8 zf = *(const us8*)(zr + 3 * HDIM);
        const float* cpr = c_prev + (size_t)cia[k] * HDIM + j8;
        float4 ca = *(const float4*)cpr;
        float4 cb = *(const float4*)(cpr + 4);
        const float cp[8] = {ca.x, ca.y, ca.z, ca.w, cb.x, cb.y, cb.z, cb.w};
#pragma unroll
        for (int j = 0; j < 8; ++j) {
            ia[j] += m * bf2f(zi[j]);
            oa[j] += m * bf2f(zo[j]);
            ua[j] += m * bf2f(zu[j]);
            fc[j] += sigf(xw[j] + m * bf2f(zf[j])) * m * cp[j];
        }
    }
    float cv[8], hv[8];
#pragma unroll
    for (int j = 0; j < 8; ++j) {
        cv[j] = sigf(ia[j]) * tanhf(ua[j]) + fc[j];
        hv[j] = sigf(oa[j]) * tanhf(cv[j]);
    }
    if (LAST) {
        *(float4*)(h_out + (size_t)n * HDIM + j8)     = make_float4(hv[0], hv[1], hv[2], hv[3]);
        *(float4*)(h_out + (size_t)n * HDIM + j8 + 4) = make_float4(hv[4], hv[5], hv[6], hv[7]);
    } else {
        *(float4*)(c_new + (size_t)n * HDIM + j8)     = make_float4(cv[0], cv[1], cv[2], cv[3]);
        *(float4*)(c_new + (size_t)n * HDIM + j8 + 4) = make_float4(cv[4], cv[5], cv[6], cv[7]);
        us8 hb;
#pragma unroll
        for (int j = 0; j < 8; ++j) hb[j] = f2bf(hv[j]);
        *(us8*)(hb_new + (size_t)n * HDIM + j8) = hb;
    }
}

// leaf: fc = 0, no children
__global__ __launch_bounds__(256) void gateleaf_k(
    const unsigned short* __restrict__ iouxW,
    float* __restrict__ c_new, unsigned short* __restrict__ hb_new)
{
    int t  = blockIdx.x * 256 + threadIdx.x;
    int n  = t >> 6;
    int j8 = (t & 63) << 3;
    const unsigned short* xr = iouxW + (size_t)n * 4 * HDIM + j8;
    us8 xi = *(const us8*)xr;
    us8 xo = *(const us8*)(xr + HDIM);
    us8 xu = *(const us8*)(xr + 2 * HDIM);
    float cv[8], hv[8];
#pragma unroll
    for (int j = 0; j < 8; ++j) {
        cv[j] = sigf(bf2f(xi[j])) * tanhf(bf2f(xu[j]));
        hv[j] = sigf(bf2f(xo[j])) * tanhf(cv[j]);
    }
    *(float4*)(c_new + (size_t)n * HDIM + j8)     = make_float4(cv[0], cv[1], cv[2], cv[3]);
    *(float4*)(c_new + (size_t)n * HDIM + j8 + 4) = make_float4(cv[4], cv[5], cv[6], cv[7]);
    us8 hb;
#pragma unroll
    for (int j = 0; j < 8; ++j) hb[j] = f2bf(hv[j]);
    *(us8*)(hb_new + (size_t)n * HDIM + j8) = hb;
}

extern "C" void kernel_launch(void* const* d_in, const int* in_sizes, int n_in,
                              void* d_out, int out_size, void* d_ws, size_t ws_size,
                              hipStream_t stream)
{
    const int*   vocab_ix   = (const int*)d_in[0];     // [L,N]
    const int*   child_idx  = (const int*)d_in[1];     // [L,N,K]
    const float* token_mask = (const float*)d_in[2];   // [L,N]
    const float* child_mask = (const float*)d_in[3];   // [L,N,K]
    const float* embed      = (const float*)d_in[4];   // [V,E] f32
    const float* W_iou      = (const float*)d_in[5];   // [E,3H]
    const float* U_iou      = (const float*)d_in[6];   // [H,3H]
    const float* b_iou      = (const float*)d_in[7];   // [3H]
    const float* W_f        = (const float*)d_in[8];   // [E,H]
    const float* U_f        = (const float*)d_in[9];   // [H,H]
    const float* b_f        = (const float*)d_in[10];  // [H]
    float* out = (float*)d_out;                        // [N,H] level-0 h

    // ---- workspace layout (~220 MB; ws is 256 MiB) ----
    float* ws = (float*)d_ws;
    float* c0 = ws;                                    // [N,H] f32
    float* c1 = c0 + (size_t)NN * HDIM;                // [N,H] f32
    unsigned short* usb   = (unsigned short*)(c1 + (size_t)NN * HDIM);
    unsigned short* hb0   = usb;                                // [N,H] bf16
    unsigned short* hb1   = hb0 + (size_t)NN * HDIM;            // [N,H] bf16
    unsigned short* iouxW = hb1 + (size_t)NN * HDIM;            // [3N,4H] bf16 (3-level batch)
    unsigned short* Z     = iouxW + (size_t)3 * NN * 4 * HDIM;  // [N,4H] bf16
    unsigned short* embB  = Z + (size_t)NN * 4 * HDIM;          // [V,EPAD] bf16
    unsigned short* WtALL = embB + (size_t)VSZ * EPAD;          // [4H,EPAD] bf16
    unsigned short* UtALL = WtALL + (size_t)4 * HDIM * EPAD;    // [4H,H] bf16

    dim3 blk(256);

    // ---- converts (every launch; ws is re-poisoned) ----
    econv_k<<<dim3(VSZ * EPAD / 256), blk, 0, stream>>>(embed, embB);
    wconv_k<<<dim3(3 * HDIM * EPAD / 256), blk, 0, stream>>>(W_iou, WtALL, EDIM, EPAD, 3 * HDIM);
    wconv_k<<<dim3(HDIM * EPAD / 256),     blk, 0, stream>>>(W_f, WtALL + (size_t)3 * HDIM * EPAD, EDIM, EPAD, HDIM);
    wconv_k<<<dim3(3 * HDIM * HDIM / 256), blk, 0, stream>>>(U_iou, UtALL, HDIM, HDIM, 3 * HDIM);
    wconv_k<<<dim3(HDIM * HDIM / 256),     blk, 0, stream>>>(U_f, UtALL + (size_t)3 * HDIM * HDIM, HDIM, HDIM, HDIM);

    unsigned short* bbuf[2] = { hb0, hb1 };
    float*          cbuf[2] = { c0,  c1  };

    const int ew_blocks = NN * HDIM / 8 / 256;   // 2048

    // Batch A: levels 3..5 (rows l-3), before the recurrence.  grid 8x192=1536 blocks
    mgemm_k<1, 1, 2><<<dim3(8, 3 * NN / BM), blk, 0, stream>>>(
        embB, vocab_ix + (size_t)3 * NN, token_mask + (size_t)3 * NN,
        WtALL, b_iou, b_f, iouxW, 4 * HDIM, EPAD);

    for (int l = LVLS - 1; l >= 0; --l) {
        const int p = (LVLS - 1 - l);            // 0..5
        unsigned short* hb_new  = bbuf[p & 1];
        float*          c_new   = cbuf[p & 1];
        unsigned short* hb_prev = bbuf[(p & 1) ^ 1];
        float*          c_prev  = cbuf[(p & 1) ^ 1];
        const int*   cix = child_idx  + (size_t)l * NN * KCH;
        const float* cm  = child_mask + (size_t)l * NN * KCH;
        const unsigned short* ix_l =
            iouxW + (size_t)((l >= 3) ? (l - 3) : l) * NN * 4 * HDIM;

        if (l == LVLS - 1) {
            gateleaf_k<<<dim3(ew_blocks), blk, 0, stream>>>(ix_l, c_new, hb_new);
        } else {
            // Z = h_prev @ [U_iou | U_f]   [8192 x 512 x 2048], grid 16x64=1024 blocks
            mgemm_k<0, 0, 1><<<dim3(16, NN / BM), blk, 0, stream>>>(
                hb_prev, nullptr, nullptr, UtALL, nullptr, nullptr, Z, 4 * HDIM, HDIM);

            if (l == 0) {
                gatefc_k<true><<<dim3(ew_blocks), blk, 0, stream>>>(
                    ix_l, Z, cix, cm, c_prev, nullptr, nullptr, out);
            } else {
                gatefc_k<false><<<dim3(ew_blocks), blk, 0, stream>>>(
                    ix_l, Z, cix, cm, c_prev, c_new, hb_new, nullptr);
            }
        }

        // After level 3 is consumed, overwrite iouxW with batch B (levels 0..2).
        if (l == 3) {
            mgemm_k<1, 1, 2><<<dim3(8, 3 * NN / BM), blk, 0, stream>>>(
                embB, vocab_ix, token_mask,
                WtALL, b_iou, b_f, iouxW, 4 * HDIM, EPAD);
        }
    }
}

// Round 6
// 772.260 us; speedup vs baseline: 1.1260x; 1.1260x over previous
//
#include <hip/hip_runtime.h>
#include <cmath>

// Problem constants: V=50000, E=300, H=512, L=6, N=8192, K=4
#define VSZ  50000
#define EDIM 300
#define EPAD 320      // E padded to multiple of 64
#define HDIM 512
#define LVLS 6
#define NN   8192
#define KCH  4

// MFMA GEMM tile: 128x128 block, BK=64, 4 waves of 64x64 (4x4 grid of 16x16x32 MFMA)
#define BM 128
#define BN 128
#define BKE 64

typedef __attribute__((ext_vector_type(8))) short bf16x8;
typedef __attribute__((ext_vector_type(8))) unsigned short us8;
typedef __attribute__((ext_vector_type(4))) float f32x4;

__device__ __forceinline__ float sigf(float x) { return 1.0f / (1.0f + expf(-x)); }

__device__ __forceinline__ unsigned short f2bf(float f) {
    unsigned u = __float_as_uint(f);
    u += 0x7FFF + ((u >> 16) & 1);           // RNE
    return (unsigned short)(u >> 16);
}
__device__ __forceinline__ float bf2f(unsigned short h) {
    return __uint_as_float(((unsigned)h) << 16);
}

// ---- convert embed [V][E] f32 -> [V][EPAD] bf16 (zero-padded) ----
__global__ __launch_bounds__(256) void econv_k(
    const float* __restrict__ in, unsigned short* __restrict__ out)
{
    int t = blockIdx.x * 256 + threadIdx.x;   // V*EPAD total
    int e = t % EPAD;
    int v = t / EPAD;
    out[t] = (e < EDIM) ? f2bf(in[(size_t)v * EDIM + e]) : (unsigned short)0;
}

// ---- transpose+convert weights: out[n][k] = bf16(in[k][n]), zero for k>=Kreal ----
__global__ __launch_bounds__(256) void wconv_k(
    const float* __restrict__ in, unsigned short* __restrict__ out,
    int Kreal, int Ksp, int Nd)
{
    int t = blockIdx.x * 256 + threadIdx.x;   // Nd*Ksp total, k fast
    int k = t % Ksp;
    int n = t / Ksp;
    out[t] = (k < Kreal) ? f2bf(in[(size_t)k * Nd + n]) : (unsigned short)0;
}

// MODEA: 0 = dense A rows, 1 = gathered rows via aidx
// EPI  : 0 = C = bf16(acc)
//        1 = C = bf16(acc*rowscale[row] + (col<1536 ? b_iou[col] : b_f[col-1536]))
// Grid: blockIdx.x = M-tile (fast-varying), blockIdx.y = N-group. Blocks sharing
// an M-tile's (gathered) A rows have linear ids m + gridDim.x*y; gridDim.x % 8 == 0
// keeps them on one XCD (round-robin heuristic) so A re-reads stay L2-local.
// BK=64: LDS granule = 16 B. Chunk c (row=c>>3, slot=c&7) holds K-granule
// kg = slot ^ (row&7); staged via global_load_lds (wave-uniform dest).
// Epilogue: acc -> bf16 via LDS (XOR swizzle), 128 B/thread contiguous stores.
// NOTE: no waves/EU clamp — acc needs 64 AGPRs; clamping to 4 waves/EU caps the
// unified VGPR+AGPR file at 128 and spills (R5: +280 MB scratch traffic).
template <int MODEA, int EPI, int NCHUNK>
__global__ __launch_bounds__(256) void mgemm_k(
    const unsigned short* __restrict__ Ab,
    const int* __restrict__ aidx, const float* __restrict__ rowscale,
    const unsigned short* __restrict__ Bt,
    const float* __restrict__ b_iou, const float* __restrict__ b_f,
    unsigned short* __restrict__ C, int ldc, int Ks)
{
    __shared__ __align__(16) unsigned short smem[2 * BM * BKE];  // 32 KB
    unsigned short* As = smem;               // [BM*BKE]
    unsigned short* Bs = smem + BM * BKE;    // [BN*BKE]

    const int tid  = threadIdx.x;
    const int wave = tid >> 6;
    const int lane = tid & 63;
    const int quad = lane >> 4;
    const int mcol = lane & 15;
    const int wm   = (wave >> 1) * 64;
    const int wn   = (wave & 1) * 64;
    const int tile_m = blockIdx.x * BM;

    // staging: 4 chunks per thread per matrix; chunk c_j = tid + 256*j
    int arow[4]; int kgo[4];
#pragma unroll
    for (int j = 0; j < 4; ++j) {
        int c   = tid + 256 * j;
        int row = c >> 3;
        kgo[j]  = ((c & 7) ^ (row & 7)) * 8;
        arow[j] = row;
    }
    const unsigned short* asrc[4];
#pragma unroll
    for (int j = 0; j < 4; ++j) {
        int gr = MODEA ? aidx[tile_m + arow[j]] : (tile_m + arow[j]);
        asrc[j] = Ab + (size_t)gr * Ks + kgo[j];
    }

    for (int nc = 0; nc < NCHUNK; ++nc) {
        const int tile_n = (blockIdx.y * NCHUNK + nc) * BN;
        const unsigned short* bsrc[4];
#pragma unroll
        for (int j = 0; j < 4; ++j)
            bsrc[j] = Bt + (size_t)(tile_n + arow[j]) * Ks + kgo[j];

        f32x4 acc[4][4] = {};

        for (int k0 = 0; k0 < Ks; k0 += BKE) {
#pragma unroll
            for (int j = 0; j < 4; ++j) {
                __attribute__((address_space(3))) unsigned int* dA =
                    (__attribute__((address_space(3))) unsigned int*)(As + (wave * 64 + 256 * j) * 8);
                __attribute__((address_space(3))) unsigned int* dB =
                    (__attribute__((address_space(3))) unsigned int*)(Bs + (wave * 64 + 256 * j) * 8);
                __builtin_amdgcn_global_load_lds(
                    (const __attribute__((address_space(1))) unsigned int*)(asrc[j] + k0), dA, 16, 0, 0);
                __builtin_amdgcn_global_load_lds(
                    (const __attribute__((address_space(1))) unsigned int*)(bsrc[j] + k0), dB, 16, 0, 0);
            }
            __syncthreads();

#pragma unroll
            for (int kh = 0; kh < 2; ++kh) {
                bf16x8 afr[4], bfr[4];
#pragma unroll
                for (int mt = 0; mt < 4; ++mt) {
                    int rw = wm + mt * 16 + mcol;
                    int p  = (kh * 4 + quad) ^ (rw & 7);
                    afr[mt] = *(const bf16x8*)(As + (rw * 8 + p) * 8);
                }
#pragma unroll
                for (int nt = 0; nt < 4; ++nt) {
                    int rw = wn + nt * 16 + mcol;
                    int p  = (kh * 4 + quad) ^ (rw & 7);
                    bfr[nt] = *(const bf16x8*)(Bs + (rw * 8 + p) * 8);
                }
#pragma unroll
                for (int mt = 0; mt < 4; ++mt)
#pragma unroll
                    for (int nt = 0; nt < 4; ++nt)
                        acc[mt][nt] = __builtin_amdgcn_mfma_f32_16x16x32_bf16(
                            afr[mt], bfr[nt], acc[mt][nt], 0, 0, 0);
            }
            __syncthreads();
        }

        // ---- epilogue: stage bf16 C-tile in LDS (16B-granule XOR swizzle on
        // row&7), then contiguous 128 B/thread readback + dwordx4 stores ----
        unsigned short* Ct = smem;   // 32 KB = 128*128 ushort
#pragma unroll
        for (int mt = 0; mt < 4; ++mt) {
            const int rl = wm + mt * 16 + quad * 4;     // local row base
            float4 ts = make_float4(1.f, 1.f, 1.f, 1.f);
            if (EPI == 1) ts = *(const float4*)&rowscale[tile_m + rl];
            const float tsv[4] = {ts.x, ts.y, ts.z, ts.w};
#pragma unroll
            for (int nt = 0; nt < 4; ++nt) {
                const int cl = wn + nt * 16 + mcol;     // local col
                float bv = 0.0f;
                if (EPI == 1) {
                    int col = tile_n + cl;
                    bv = (col < 3 * HDIM) ? b_iou[col] : b_f[col - 3 * HDIM];
                }
#pragma unroll
                for (int r = 0; r < 4; ++r) {
                    int row = rl + r;
                    int g   = (cl >> 3) ^ (row & 7);    // swizzled 16B granule
                    float v = acc[mt][nt][r];
                    if (EPI == 1) v = v * tsv[r] + bv;
                    Ct[row * BN + g * 8 + (cl & 7)] = f2bf(v);
                }
            }
        }
        __syncthreads();
        {
            const int row  = tid >> 1;
            const int half = tid & 1;
            unsigned short* gp = C + (size_t)(tile_m + row) * ldc + tile_n + half * 64;
#pragma unroll
            for (int v = 0; v < 8; ++v) {
                int g  = half * 8 + v;
                int gs = g ^ (row & 7);
                *(us8*)(gp + v * 8) = *(const us8*)(Ct + row * BN + gs * 8);
            }
        }
        __syncthreads();   // LDS reused for staging next nc chunk
    }
}

// fused child-sum + fc + gates (non-leaf).
// iouxW row: bf16 [i|o|u|xwf+bf] (2048). Z row: bf16 [h@U_iou (1536) | h@U_f (512)].
//   ia = i + sum_k m_k * Zi[c_k] ; fc = sum_k sigf(xw + m_k*Zf[c_k]) * m_k * c_prev[c_k]
//   c = sigf(ia)*tanh(ua) + fc ; h = sigf(oa)*tanh(c)
template <bool LAST>
__global__ __launch_bounds__(256) void gatefc_k(
    const unsigned short* __restrict__ iouxW, const unsigned short* __restrict__ Z,
    const int* __restrict__ cidx, const float* __restrict__ cmask,
    const float* __restrict__ c_prev,
    float* __restrict__ c_new, unsigned short* __restrict__ hb_new,
    float* __restrict__ h_out)
{
    int t  = blockIdx.x * 256 + threadIdx.x;   // NN*HDIM/8 threads
    int n  = t >> 6;
    int j8 = (t & 63) << 3;
    const unsigned short* xr = iouxW + (size_t)n * 4 * HDIM + j8;
    us8 xi = *(const us8*)xr;
    us8 xo = *(const us8*)(xr + HDIM);
    us8 xu = *(const us8*)(xr + 2 * HDIM);
    us8 xf = *(const us8*)(xr + 3 * HDIM);
    float ia[8], oa[8], ua[8], xw[8], fc[8];
#pragma unroll
    for (int j = 0; j < 8; ++j) {
        ia[j] = bf2f(xi[j]); oa[j] = bf2f(xo[j]);
        ua[j] = bf2f(xu[j]); xw[j] = bf2f(xf[j]);
        fc[j] = 0.0f;
    }
    int4   ci = *(const int4*)&cidx[n * KCH];
    float4 cm = *(const float4*)&cmask[n * KCH];
    const int   cia[4] = {ci.x, ci.y, ci.z, ci.w};
    const float cma[4] = {cm.x, cm.y, cm.z, cm.w};
#pragma unroll
    for (int k = 0; k < KCH; ++k) {
        const float m = cma[k];
        const unsigned short* zr = Z + (size_t)cia[k] * 4 * HDIM + j8;
        us8 zi = *(const us8*)zr;
        us8 zo = *(const us8*)(zr + HDIM);
        us8 zu = *(const us8*)(zr + 2 * HDIM);
        us8 zf = *(const us8*)(zr + 3 * HDIM);
        const float* cpr = c_prev + (size_t)cia[k] * HDIM + j8;
        float4 ca = *(const float4*)cpr;
        float4 cb = *(const float4*)(cpr + 4);
        const float cp[8] = {ca.x, ca.y, ca.z, ca.w, cb.x, cb.y, cb.z, cb.w};
#pragma unroll
        for (int j = 0; j < 8; ++j) {
            ia[j] += m * bf2f(zi[j]);
            oa[j] += m * bf2f(zo[j]);
            ua[j] += m * bf2f(zu[j]);
            fc[j] += sigf(xw[j] + m * bf2f(zf[j])) * m * cp[j];
        }
    }
    float cv[8], hv[8];
#pragma unroll
    for (int j = 0; j < 8; ++j) {
        cv[j] = sigf(ia[j]) * tanhf(ua[j]) + fc[j];
        hv[j] = sigf(oa[j]) * tanhf(cv[j]);
    }
    if (LAST) {
        *(float4*)(h_out + (size_t)n * HDIM + j8)     = make_float4(hv[0], hv[1], hv[2], hv[3]);
        *(float4*)(h_out + (size_t)n * HDIM + j8 + 4) = make_float4(hv[4], hv[5], hv[6], hv[7]);
    } else {
        *(float4*)(c_new + (size_t)n * HDIM + j8)     = make_float4(cv[0], cv[1], cv[2], cv[3]);
        *(float4*)(c_new + (size_t)n * HDIM + j8 + 4) = make_float4(cv[4], cv[5], cv[6], cv[7]);
        us8 hb;
#pragma unroll
        for (int j = 0; j < 8; ++j) hb[j] = f2bf(hv[j]);
        *(us8*)(hb_new + (size_t)n * HDIM + j8) = hb;
    }
}

// leaf: fc = 0, no children
__global__ __launch_bounds__(256) void gateleaf_k(
    const unsigned short* __restrict__ iouxW,
    float* __restrict__ c_new, unsigned short* __restrict__ hb_new)
{
    int t  = blockIdx.x * 256 + threadIdx.x;
    int n  = t >> 6;
    int j8 = (t & 63) << 3;
    const unsigned short* xr = iouxW + (size_t)n * 4 * HDIM + j8;
    us8 xi = *(const us8*)xr;
    us8 xo = *(const us8*)(xr + HDIM);
    us8 xu = *(const us8*)(xr + 2 * HDIM);
    float cv[8], hv[8];
#pragma unroll
    for (int j = 0; j < 8; ++j) {
        cv[j] = sigf(bf2f(xi[j])) * tanhf(bf2f(xu[j]));
        hv[j] = sigf(bf2f(xo[j])) * tanhf(cv[j]);
    }
    *(float4*)(c_new + (size_t)n * HDIM + j8)     = make_float4(cv[0], cv[1], cv[2], cv[3]);
    *(float4*)(c_new + (size_t)n * HDIM + j8 + 4) = make_float4(cv[4], cv[5], cv[6], cv[7]);
    us8 hb;
#pragma unroll
    for (int j = 0; j < 8; ++j) hb[j] = f2bf(hv[j]);
    *(us8*)(hb_new + (size_t)n * HDIM + j8) = hb;
}

extern "C" void kernel_launch(void* const* d_in, const int* in_sizes, int n_in,
                              void* d_out, int out_size, void* d_ws, size_t ws_size,
                              hipStream_t stream)
{
    const int*   vocab_ix   = (const int*)d_in[0];     // [L,N]
    const int*   child_idx  = (const int*)d_in[1];     // [L,N,K]
    const float* token_mask = (const float*)d_in[2];   // [L,N]
    const float* child_mask = (const float*)d_in[3];   // [L,N,K]
    const float* embed      = (const float*)d_in[4];   // [V,E] f32
    const float* W_iou      = (const float*)d_in[5];   // [E,3H]
    const float* U_iou      = (const float*)d_in[6];   // [H,3H]
    const float* b_iou      = (const float*)d_in[7];   // [3H]
    const float* W_f        = (const float*)d_in[8];   // [E,H]
    const float* U_f        = (const float*)d_in[9];   // [H,H]
    const float* b_f        = (const float*)d_in[10];  // [H]
    float* out = (float*)d_out;                        // [N,H] level-0 h

    // ---- workspace layout (~220 MB; ws is 256 MiB) ----
    float* ws = (float*)d_ws;
    float* c0 = ws;                                    // [N,H] f32
    float* c1 = c0 + (size_t)NN * HDIM;                // [N,H] f32
    unsigned short* usb   = (unsigned short*)(c1 + (size_t)NN * HDIM);
    unsigned short* hb0   = usb;                                // [N,H] bf16
    unsigned short* hb1   = hb0 + (size_t)NN * HDIM;            // [N,H] bf16
    unsigned short* iouxW = hb1 + (size_t)NN * HDIM;            // [3N,4H] bf16 (3-level batch)
    unsigned short* Z     = iouxW + (size_t)3 * NN * 4 * HDIM;  // [N,4H] bf16
    unsigned short* embB  = Z + (size_t)NN * 4 * HDIM;          // [V,EPAD] bf16
    unsigned short* WtALL = embB + (size_t)VSZ * EPAD;          // [4H,EPAD] bf16
    unsigned short* UtALL = WtALL + (size_t)4 * HDIM * EPAD;    // [4H,H] bf16

    dim3 blk(256);

    // ---- converts (every launch; ws is re-poisoned) ----
    econv_k<<<dim3(VSZ * EPAD / 256), blk, 0, stream>>>(embed, embB);
    wconv_k<<<dim3(3 * HDIM * EPAD / 256), blk, 0, stream>>>(W_iou, WtALL, EDIM, EPAD, 3 * HDIM);
    wconv_k<<<dim3(HDIM * EPAD / 256),     blk, 0, stream>>>(W_f, WtALL + (size_t)3 * HDIM * EPAD, EDIM, EPAD, HDIM);
    wconv_k<<<dim3(3 * HDIM * HDIM / 256), blk, 0, stream>>>(U_iou, UtALL, HDIM, HDIM, 3 * HDIM);
    wconv_k<<<dim3(HDIM * HDIM / 256),     blk, 0, stream>>>(U_f, UtALL + (size_t)3 * HDIM * HDIM, HDIM, HDIM, HDIM);

    unsigned short* bbuf[2] = { hb0, hb1 };
    float*          cbuf[2] = { c0,  c1  };

    const int ew_blocks = NN * HDIM / 8 / 256;   // 2048

    // Batch A: levels 3..5 (rows l-3), before the recurrence.
    // grid (192, 8): x = M-tile (same-A blocks land on one XCD), y = N-group.
    mgemm_k<1, 1, 2><<<dim3(3 * NN / BM, 8), blk, 0, stream>>>(
        embB, vocab_ix + (size_t)3 * NN, token_mask + (size_t)3 * NN,
        WtALL, b_iou, b_f, iouxW, 4 * HDIM, EPAD);

    for (int l = LVLS - 1; l >= 0; --l) {
        const int p = (LVLS - 1 - l);            // 0..5
        unsigned short* hb_new  = bbuf[p & 1];
        float*          c_new   = cbuf[p & 1];
        unsigned short* hb_prev = bbuf[(p & 1) ^ 1];
        float*          c_prev  = cbuf[(p & 1) ^ 1];
        const int*   cix = child_idx  + (size_t)l * NN * KCH;
        const float* cm  = child_mask + (size_t)l * NN * KCH;
        const unsigned short* ix_l =
            iouxW + (size_t)((l >= 3) ? (l - 3) : l) * NN * 4 * HDIM;

        if (l == LVLS - 1) {
            gateleaf_k<<<dim3(ew_blocks), blk, 0, stream>>>(ix_l, c_new, hb_new);
        } else {
            // Z = h_prev @ [U_iou | U_f]   [8192 x 512 x 2048], grid (64, 8)
            mgemm_k<0, 0, 2><<<dim3(NN / BM, 8), blk, 0, stream>>>(
                hb_prev, nullptr, nullptr, UtALL, nullptr, nullptr, Z, 4 * HDIM, HDIM);

            if (l == 0) {
                gatefc_k<true><<<dim3(ew_blocks), blk, 0, stream>>>(
                    ix_l, Z, cix, cm, c_prev, nullptr, nullptr, out);
            } else {
                gatefc_k<false><<<dim3(ew_blocks), blk, 0, stream>>>(
                    ix_l, Z, cix, cm, c_prev, c_new, hb_new, nullptr);
            }
        }

        // After level 3 is consumed, overwrite iouxW with batch B (levels 0..2).
        if (l == 3) {
            mgemm_k<1, 1, 2><<<dim3(3 * NN / BM, 8), blk, 0, stream>>>(
                embB, vocab_ix, token_mask,
                WtALL, b_iou, b_f, iouxW, 4 * HDIM, EPAD);
        }
    }
}